// Round 4
// baseline (1156.200 us; speedup 1.0000x reference)
//
#include <hip/hip_runtime.h>
#include <hip/hip_bf16.h>

#define NV 10000
#define PADM 10112   // 79*128, fc3 tiling pad

typedef __attribute__((ext_vector_type(8))) short bf16x8;
typedef __attribute__((ext_vector_type(4))) float f32x4;

__device__ __forceinline__ void g2l16(const void* g, void* l) {
  __builtin_amdgcn_global_load_lds((__attribute__((address_space(1))) void*)(void*)g,
                                   (__attribute__((address_space(3))) void*)l, 16, 0, 0);
}

// ---------------- generic fp32 GEMM: Y = [A1|A2] @ B + bias, + column stats ----------------
// grid.x = ceil(M/64), grid.y = N/64, block 256. K1,K2 multiples of 32; N multiple of 64.
__global__ __launch_bounds__(256) void gemm_f32(
    const float* __restrict__ A1, int K1, const float* __restrict__ A2, int K2,
    const float* __restrict__ B, const float* __restrict__ bias,
    float* __restrict__ Y, float* __restrict__ stats, int N)
{
  __shared__ float As[64][36];   // stride 36: 16B-aligned rows, 2-way-max bank aliasing
  __shared__ float Bs[32][68];
  const int tid = threadIdx.x;
  const int row0 = blockIdx.x * 64;
  const int n0 = blockIdx.y * 64;
  const int tr = tid >> 4, tc = tid & 15;
  const int Ktot = K1 + K2;
  float acc[4][4];
#pragma unroll
  for (int i = 0; i < 4; ++i)
#pragma unroll
    for (int j = 0; j < 4; ++j) acc[i][j] = 0.f;

  for (int k0 = 0; k0 < Ktot; k0 += 32) {
    const float* Ap; int lda, ka;
    if (k0 < K1) { Ap = A1; lda = K1; ka = k0; }
    else         { Ap = A2; lda = K2; ka = k0 - K1; }
    __syncthreads();
    {
      int r = tid >> 3, seg = tid & 7;
#pragma unroll
      for (int h = 0; h < 2; ++h) {
        int rr = r + h * 32;
        int gr = row0 + rr; if (gr > NV - 1) gr = NV - 1;  // clamp; stores guarded
        float4 v = *(const float4*)(Ap + (size_t)gr * lda + ka + seg * 4);
        *(float4*)&As[rr][seg * 4] = v;
      }
      int kr = tid >> 4, cseg = tid & 15;
#pragma unroll
      for (int h = 0; h < 2; ++h) {
        int kk = kr + h * 16;
        float4 v = *(const float4*)(B + (size_t)(k0 + kk) * N + n0 + cseg * 4);
        *(float4*)&Bs[kk][cseg * 4] = v;
      }
    }
    __syncthreads();
#pragma unroll 8
    for (int kk = 0; kk < 32; ++kk) {
      float4 bv = *(const float4*)&Bs[kk][tc * 4];
#pragma unroll
      for (int i = 0; i < 4; ++i) {
        float a = As[tr * 4 + i][kk];
        acc[i][0] = fmaf(a, bv.x, acc[i][0]);
        acc[i][1] = fmaf(a, bv.y, acc[i][1]);
        acc[i][2] = fmaf(a, bv.z, acc[i][2]);
        acc[i][3] = fmaf(a, bv.w, acc[i][3]);
      }
    }
  }
  float bvv[4];
#pragma unroll
  for (int j = 0; j < 4; ++j) bvv[j] = bias[n0 + tc * 4 + j];
  float cs[4] = {0.f, 0.f, 0.f, 0.f}, cq[4] = {0.f, 0.f, 0.f, 0.f};
#pragma unroll
  for (int i = 0; i < 4; ++i) {
    int gr = row0 + tr * 4 + i;
    bool ok = gr < NV;
    float o[4];
#pragma unroll
    for (int j = 0; j < 4; ++j) {
      float v = acc[i][j] + bvv[j];
      o[j] = v;
      if (ok) { cs[j] += v; cq[j] += v * v; }
    }
    if (ok) *(float4*)(Y + (size_t)gr * N + n0 + tc * 4) = make_float4(o[0], o[1], o[2], o[3]);
  }
  // block-level column stat reduction, then one atomic per column
  __syncthreads();
  float* red = &As[0][0];  // reuse: need 2176 <= 2304 floats
#pragma unroll
  for (int j = 0; j < 4; ++j) {
    red[tr * 68 + tc * 4 + j] = cs[j];
    red[1088 + tr * 68 + tc * 4 + j] = cq[j];
  }
  __syncthreads();
  if (tid < 64) {
    float s = 0.f, q = 0.f;
#pragma unroll
    for (int t = 0; t < 16; ++t) { s += red[t * 68 + tid]; q += red[1088 + t * 68 + tid]; }
    atomicAdd(&stats[n0 + tid], s);
    atomicAdd(&stats[256 + n0 + tid], q);
  }
}

// ---------------- BN(training stats) + ReLU; optional bf16 secondary output ----------------
__global__ __launch_bounds__(256) void bn_relu(
    const float* __restrict__ Y, const float* __restrict__ stats,
    const float* __restrict__ g, const float* __restrict__ bt,
    float* __restrict__ out, unsigned short* __restrict__ outb, int C)
{
  int gid = blockIdx.x * 256 + threadIdx.x;
  int total = NV * (C >> 2);
  if (gid >= total) return;
  int c = (gid * 4) % C;
  float4 y = *(const float4*)(Y + (size_t)gid * 4);
  float vy[4] = {y.x, y.y, y.z, y.w};
  float o[4];
#pragma unroll
  for (int j = 0; j < 4; ++j) {
    int cc = c + j;
    float mean = stats[cc] * 1e-4f;
    float var  = stats[256 + cc] * 1e-4f - mean * mean;
    float sc = rsqrtf(var + 1e-3f) * g[cc];
    float sh = bt[cc] - mean * sc;
    o[j] = fmaxf(0.f, fmaf(vy[j], sc, sh));
  }
  *(float4*)(out + (size_t)gid * 4) = make_float4(o[0], o[1], o[2], o[3]);
  if (outb != nullptr) {
    unsigned short u[4];
#pragma unroll
    for (int j = 0; j < 4; ++j) {
      __hip_bfloat16 h = __float2bfloat16(o[j]);
      u[j] = *(unsigned short*)&h;
    }
    *(ushort2*)(outb + (size_t)gid * 4)     = make_ushort2(u[0], u[1]);
    *(ushort2*)(outb + (size_t)gid * 4 + 2) = make_ushort2(u[2], u[3]);
  }
}

// ---------------- split-K [64,10000]@[10000,64] -> atomic accumulate into outm[4096] ----------------
__global__ __launch_bounds__(256) void dx_atomic(
    const float* __restrict__ Dm, const float* __restrict__ X, float* __restrict__ outm)
{
  __shared__ float Ds[64][40];
  __shared__ float Xs[40][64];
  const int tid = threadIdx.x;
  const int k0 = blockIdx.x * 40;
  const float* xp = X + (size_t)k0 * 64;
  for (int i = tid; i < 2560; i += 256) ((float*)Xs)[i] = xp[i];
  {
    int r = tid >> 2, qq = tid & 3;
#pragma unroll
    for (int m = 0; m < 10; ++m) Ds[r][qq + 4 * m] = Dm[(size_t)r * NV + k0 + qq + 4 * m];
  }
  __syncthreads();
  const int j = tid & 63, ig = tid >> 6;
  float acc[16];
#pragma unroll
  for (int ii = 0; ii < 16; ++ii) acc[ii] = 0.f;
  for (int k = 0; k < 40; ++k) {
    float xv = Xs[k][j];
#pragma unroll
    for (int ii = 0; ii < 16; ++ii) acc[ii] = fmaf(Ds[ig * 16 + ii][k], xv, acc[ii]);
  }
  float* op = outm + (size_t)ig * 1024 + j;
#pragma unroll
  for (int ii = 0; ii < 16; ++ii) atomicAdd(&op[ii * 64], acc[ii]);
}

// ---------------- layer-independent A_k chain: A_{k+1} = 2E(a_k I + DV A_k) - A_{k-1} ----------------
__global__ __launch_bounds__(256) void chainA(
    const float* __restrict__ DVm, const float* __restrict__ eigs, float* __restrict__ Acat)
{
  __shared__ float DVL[64][68];
  __shared__ float AL[3][64][68];
  __shared__ float ev[64];
  const int tid = threadIdx.x;
  for (int i = tid; i < 4096; i += 256) DVL[i >> 6][i & 63] = DVm[i];
  if (tid < 64) ev[tid] = eigs[tid];
  __syncthreads();
  for (int i = tid; i < 4096; i += 256) {
    int r = i >> 6, c = i & 63;
    AL[0][r][c] = 0.f;
    float v = (r == c) ? ev[r] : 0.f;   // A_1 = diag(eigs)
    AL[1][r][c] = v;
    Acat[i] = v;
  }
  __syncthreads();
  const int tr = tid >> 4, tc = tid & 15;
  float aK[4]; aK[0] = 0.f; aK[1] = -1.f; aK[2] = 0.f; aK[3] = 1.f;  // a_1..a_4
  for (int k = 1; k <= 4; ++k) {
    int cur = k % 3, prv = (k - 1) % 3, nxt = (k + 1) % 3;
    float g4[4][4];
#pragma unroll
    for (int ii = 0; ii < 4; ++ii)
#pragma unroll
      for (int jj = 0; jj < 4; ++jj) g4[ii][jj] = 0.f;
    for (int p = 0; p < 64; ++p) {
      float4 av = *(const float4*)&AL[cur][p][tc * 4];
#pragma unroll
      for (int ii = 0; ii < 4; ++ii) {
        float dv = DVL[tr * 4 + ii][p];
        g4[ii][0] = fmaf(dv, av.x, g4[ii][0]);
        g4[ii][1] = fmaf(dv, av.y, g4[ii][1]);
        g4[ii][2] = fmaf(dv, av.z, g4[ii][2]);
        g4[ii][3] = fmaf(dv, av.w, g4[ii][3]);
      }
    }
    float ak = aK[k - 1];
#pragma unroll
    for (int ii = 0; ii < 4; ++ii) {
      int i = tr * 4 + ii;
#pragma unroll
      for (int jj = 0; jj < 4; ++jj) {
        int j = tc * 4 + jj;
        float gg = g4[ii][jj] + ((i == j) ? ak : 0.f);
        float v = 2.f * ev[i] * gg - AL[prv][i][j];
        AL[nxt][i][j] = v;
        Acat[(size_t)k * 4096 + i * 64 + j] = v;
      }
    }
    __syncthreads();
  }
}

// ---------------- per-layer: M_k = A_k @ S0 -> Mcat[64][320] ----------------
__global__ __launch_bounds__(256) void mcat_k(
    const float* __restrict__ Acat, const float* __restrict__ S0, float* __restrict__ Mcat)
{
  __shared__ float AL[64][68];
  __shared__ float SL[64][68];
  const int kb = blockIdx.x;  // 0..4
  const int tid = threadIdx.x;
  for (int i = tid; i < 4096; i += 256) {
    AL[i >> 6][i & 63] = Acat[(size_t)kb * 4096 + i];
    SL[i >> 6][i & 63] = S0[i];
  }
  __syncthreads();
  const int tr = tid >> 4, tc = tid & 15;
  float g4[4][4];
#pragma unroll
  for (int ii = 0; ii < 4; ++ii)
#pragma unroll
    for (int jj = 0; jj < 4; ++jj) g4[ii][jj] = 0.f;
  for (int p = 0; p < 64; ++p) {
    float4 sv = *(const float4*)&SL[p][tc * 4];
#pragma unroll
    for (int ii = 0; ii < 4; ++ii) {
      float a = AL[tr * 4 + ii][p];
      g4[ii][0] = fmaf(a, sv.x, g4[ii][0]);
      g4[ii][1] = fmaf(a, sv.y, g4[ii][1]);
      g4[ii][2] = fmaf(a, sv.z, g4[ii][2]);
      g4[ii][3] = fmaf(a, sv.w, g4[ii][3]);
    }
  }
#pragma unroll
  for (int ii = 0; ii < 4; ++ii)
#pragma unroll
    for (int jj = 0; jj < 4; ++jj)
      Mcat[(size_t)(tr * 4 + ii) * 320 + kb * 64 + tc * 4 + jj] = g4[ii][jj];
}

// ---------------- Bc = [Wh ; Mout]: Wh = W0-W2+W4, Mout = Mcat @ W[1:6] ----------------
__global__ __launch_bounds__(256) void bc_k(
    const float* __restrict__ W, const float* __restrict__ Mcat,
    float* __restrict__ Bc, int Cout)
{
  int e = blockIdx.x * 256 + threadIdx.x;   // grid sized to 128*Cout exactly
  int row = e / Cout, j = e - row * Cout;
  if (row < 64) {
    Bc[e] = W[row * Cout + j] - W[128 * Cout + row * Cout + j] + W[256 * Cout + row * Cout + j];
  } else {
    int i = row - 64;
    const float* wc = W + 64 * Cout + j;
    const float* mr = Mcat + (size_t)i * 320;
    float s = 0.f;
#pragma unroll 8
    for (int qq = 0; qq < 320; ++qq) s = fmaf(mr[qq], wc[(size_t)qq * Cout], s);
    Bc[e] = s;
  }
}

// ---------------- fc3_w [256][10000] fp32 -> wT [10112][256] bf16 (zero pad) ----------------
__global__ __launch_bounds__(256) void cast_transpose_w(
    const float* __restrict__ w, unsigned short* __restrict__ wT)
{
  __shared__ float tile[32][33];
  int n0 = blockIdx.x * 32, k0 = blockIdx.y * 32;
  int t = threadIdx.x;
  int rr = t >> 5, cc = t & 31;
#pragma unroll
  for (int p = 0; p < 4; ++p) {
    int k = k0 + rr + p * 8, n = n0 + cc;
    tile[rr + p * 8][cc] = (n < NV) ? w[(size_t)k * NV + n] : 0.f;
  }
  __syncthreads();
#pragma unroll
  for (int p = 0; p < 4; ++p) {
    int n = n0 + rr + p * 8, k = k0 + cc;
    __hip_bfloat16 h = __float2bfloat16(tile[cc][rr + p * 8]);
    wT[(size_t)n * 256 + k] = *(unsigned short*)&h;
  }
}

// ---------------- fc3 GEMM, T3-pipelined (double-buffered LDS, 1 barrier/K-step) ----------
// WRITE=false: rowsum[r] += sum_c exp(logit-20), no stores.
// WRITE=true : recompute logits, store normalized log_softmax directly.
// LDS XOR-swizzled (T2): linear g2l16 dest + swizzled GLOBAL source column; read kb ^ ((row&7)<<3).
template<bool WRITE>
__global__ __launch_bounds__(256) void fc3_k(
    const unsigned short* __restrict__ A, const unsigned short* __restrict__ Bt,
    const float* __restrict__ bias, float* __restrict__ rowsum,
    float* __restrict__ out)
{
  __shared__ unsigned short As[2][128 * 64];
  __shared__ unsigned short Bs[2][128 * 64];
  const int tid = threadIdx.x;
  const int wv = tid >> 6, lane = tid & 63;
  const int row0 = blockIdx.x * 128, col0 = blockIdx.y * 128;
  const int wr = wv >> 1, wc = wv & 1;
  f32x4 acc[4][4];
#pragma unroll
  for (int i = 0; i < 4; ++i)
#pragma unroll
    for (int j = 0; j < 4; ++j)
#pragma unroll
      for (int e = 0; e < 4; ++e) acc[i][j][e] = 0.f;

  const int rs = wv * 8 + (lane >> 3);                   // 0..31 row-in-group
  const int csg = (lane & 7) * 8;                        // LDS dest col (linear, HW order)
  const int gsg = ((lane & 7) ^ (lane >> 3)) * 8;        // swizzled global source col
  const int swz = (lane & 7) << 3;                       // read-side XOR (row&7)<<3
  const unsigned short* Ag = A  + (size_t)(row0 + rs) * 256 + gsg;
  const unsigned short* Bg = Bt + (size_t)(col0 + rs) * 256 + gsg;
  const int mbase = wr * 64 + (lane & 15);
  const int nbase = wc * 64 + (lane & 15);

  // prologue: stage tile 0 into buf 0
#pragma unroll
  for (int i = 0; i < 4; ++i) {
    g2l16(Ag + (size_t)(i * 32) * 256, &As[0][(i * 32 + rs) * 64 + csg]);
    g2l16(Bg + (size_t)(i * 32) * 256, &Bs[0][(i * 32 + rs) * 64 + csg]);
  }
#pragma unroll
  for (int t = 0; t < 4; ++t) {
    // __syncthreads drains vmcnt (tile t resident for all waves) and
    // WAR-protects buf (t+1)&1 (all waves done computing it at t-1).
    __syncthreads();
    if (t < 3) {
      const int b = (t + 1) & 1, kt = (t + 1) * 64;
#pragma unroll
      for (int i = 0; i < 4; ++i) {
        g2l16(Ag + (size_t)(i * 32) * 256 + kt, &As[b][(i * 32 + rs) * 64 + csg]);
        g2l16(Bg + (size_t)(i * 32) * 256 + kt, &Bs[b][(i * 32 + rs) * 64 + csg]);
      }
    }
    __builtin_amdgcn_s_setprio(1);
#pragma unroll
    for (int kk = 0; kk < 2; ++kk) {
      const int kb = (kk * 32 + (lane >> 4) * 8) ^ swz;
      bf16x8 af[4], bf[4];
#pragma unroll
      for (int mi = 0; mi < 4; ++mi) af[mi] = *(const bf16x8*)&As[t & 1][(mbase + mi * 16) * 64 + kb];
#pragma unroll
      for (int ni = 0; ni < 4; ++ni) bf[ni] = *(const bf16x8*)&Bs[t & 1][(nbase + ni * 16) * 64 + kb];
#pragma unroll
      for (int mi = 0; mi < 4; ++mi)
#pragma unroll
        for (int ni = 0; ni < 4; ++ni)
          acc[mi][ni] = __builtin_amdgcn_mfma_f32_16x16x32_bf16(af[mi], bf[ni], acc[mi][ni], 0, 0, 0);
    }
    __builtin_amdgcn_s_setprio(0);
  }
  const int q = lane >> 4, cl = lane & 15;
#pragma unroll
  for (int mi = 0; mi < 4; ++mi) {
#pragma unroll
    for (int r = 0; r < 4; ++r) {
      int grow = row0 + wr * 64 + mi * 16 + q * 4 + r;
      if (WRITE) {
        if (grow < NV) {
          float l = 20.f + __logf(rowsum[grow]);
#pragma unroll
          for (int ni = 0; ni < 4; ++ni) {
            int gcol = col0 + wc * 64 + ni * 16 + cl;
            if (gcol < NV)
              out[(size_t)grow * NV + gcol] = acc[mi][ni][r] + bias[gcol] - l;
          }
        }
      } else {
        float ps = 0.f;
        if (grow < NV) {
#pragma unroll
          for (int ni = 0; ni < 4; ++ni) {
            int gcol = col0 + wc * 64 + ni * 16 + cl;
            if (gcol < NV) ps += __expf(acc[mi][ni][r] + bias[gcol] - 20.f);
          }
        }
#pragma unroll
        for (int s = 1; s < 16; s <<= 1) ps += __shfl_xor(ps, s, 64);
        if (cl == 0 && grow < NV) atomicAdd(&rowsum[grow], ps);
      }
    }
  }
}

extern "C" void kernel_launch(void* const* d_in, const int* in_sizes, int n_in,
                              void* d_out, int out_size, void* d_ws, size_t ws_size,
                              hipStream_t stream)
{
  const float* x     = (const float*)d_in[0];
  const float* V     = (const float*)d_in[1];
  const float* D     = (const float*)d_in[2];
  const float* eigs  = (const float*)d_in[3];
  const float* fc1_w = (const float*)d_in[4];
  const float* fc1_b = (const float*)d_in[5];
  const float* bf1_g = (const float*)d_in[6];
  const float* bf1_b = (const float*)d_in[7];
  const float* W1    = (const float*)d_in[8];
  const float* cb1   = (const float*)d_in[9];
  const float* b1_g  = (const float*)d_in[10];
  const float* b1_b  = (const float*)d_in[11];
  const float* W2    = (const float*)d_in[12];
  const float* cb2   = (const float*)d_in[13];
  const float* b2_g  = (const float*)d_in[14];
  const float* b2_b  = (const float*)d_in[15];
  const float* W3    = (const float*)d_in[16];
  const float* cb3   = (const float*)d_in[17];
  const float* b3_g  = (const float*)d_in[18];
  const float* b3_b  = (const float*)d_in[19];
  const float* fc2_w = (const float*)d_in[20];
  const float* fc2_b = (const float*)d_in[21];
  const float* bf2_g = (const float*)d_in[22];
  const float* bf2_b = (const float*)d_in[23];
  const float* fc3_w = (const float*)d_in[24];
  const float* fc3_b = (const float*)d_in[25];
  (void)in_sizes; (void)n_in; (void)out_size;

  float* ws = (float*)d_ws;
  float* rowsum = ws;                 // [10000]          (zeroed)
  float* stats  = ws + 10000;         // [5][512]         (zeroed)
  float* DVm    = ws + 12560;         // [4096]           (zeroed, atomic acc)
  float* S0a    = ws + 16656;         // [4096]           (zeroed, atomic acc)
  float* S0b    = ws + 20752;         // [4096]           (zeroed, atomic acc)
  float* S0c    = ws + 24848;         // [4096]           (zeroed, atomic acc)
  float* Acat   = ws + 28944;         // [5*4096]
  float* Mcat   = ws + 49424;         // [64*320]
  float* Bc     = ws + 69904;         // [128*128]
  float* Ybuf   = ws + 86288;         // [10000*256]
  float* actA   = ws + 2646288;       // [10000*64]
  float* actB   = ws + 3286288;       // [10000*64]
  float* h3     = ws + 3926288;       // [10000*128]
  unsigned short* descb = (unsigned short*)(ws + 5206288);  // [10112*256] bf16
  unsigned short* wT    = (unsigned short*)(ws + 6500624);  // [10112*256] bf16
  if (ws_size < (size_t)7794960 * 4) return;  // need ~31.2 MB

  float* out_lsm  = (float*)d_out;
  float* out_desc = out_lsm + (size_t)100000000;

  // zero accumulators (rowsum, stats, DVm, S0a/b/c) + bf16 pad rows of desc
  hipMemsetAsync(ws, 0, 28944 * sizeof(float), stream);
  hipMemsetAsync(descb + (size_t)NV * 256, 0, (size_t)(PADM - NV) * 256 * 2, stream);

  cast_transpose_w<<<dim3(316, 8), 256, 0, stream>>>(fc3_w, wT);

  // DV = D @ V, then the layer-independent A_k chain
  dx_atomic<<<250, 256, 0, stream>>>(D, V, DVm);
  chainA<<<1, 256, 0, stream>>>(DVm, eigs, Acat);

  // fc1 + BN + relu
  gemm_f32<<<dim3(157, 1), 256, 0, stream>>>(x, 352, nullptr, 0, fc1_w, fc1_b,
                                             Ybuf, stats + 0 * 512, 64);
  bn_relu<<<625, 256, 0, stream>>>(Ybuf, stats + 0 * 512, bf1_g, bf1_b, actA, nullptr, 64);

  // cheb layer 1 (in actA -> out actB)
  dx_atomic<<<250, 256, 0, stream>>>(D, actA, S0a);
  mcat_k<<<5, 256, 0, stream>>>(Acat, S0a, Mcat);
  bc_k<<<32, 256, 0, stream>>>(W1, Mcat, Bc, 64);
  gemm_f32<<<dim3(157, 1), 256, 0, stream>>>(actA, 64, V, 64, Bc, cb1,
                                             Ybuf, stats + 1 * 512, 64);
  bn_relu<<<625, 256, 0, stream>>>(Ybuf, stats + 1 * 512, b1_g, b1_b, actB, nullptr, 64);

  // cheb layer 2 (actB -> actA)
  dx_atomic<<<250, 256, 0, stream>>>(D, actB, S0b);
  mcat_k<<<5, 256, 0, stream>>>(Acat, S0b, Mcat);
  bc_k<<<32, 256, 0, stream>>>(W2, Mcat, Bc, 64);
  gemm_f32<<<dim3(157, 1), 256, 0, stream>>>(actB, 64, V, 64, Bc, cb2,
                                             Ybuf, stats + 2 * 512, 64);
  bn_relu<<<625, 256, 0, stream>>>(Ybuf, stats + 2 * 512, b2_g, b2_b, actA, nullptr, 64);

  // cheb layer 3 (actA -> h3, Cout=128)
  dx_atomic<<<250, 256, 0, stream>>>(D, actA, S0c);
  mcat_k<<<5, 256, 0, stream>>>(Acat, S0c, Mcat);
  bc_k<<<64, 256, 0, stream>>>(W3, Mcat, Bc, 128);
  gemm_f32<<<dim3(157, 2), 256, 0, stream>>>(actA, 64, V, 64, Bc, cb3,
                                             Ybuf, stats + 3 * 512, 128);
  bn_relu<<<1250, 256, 0, stream>>>(Ybuf, stats + 3 * 512, b3_g, b3_b, h3, nullptr, 128);

  // fc2 + BN + relu -> desc (fp32 to d_out, bf16 to ws)
  gemm_f32<<<dim3(157, 4), 256, 0, stream>>>(h3, 128, nullptr, 0, fc2_w, fc2_b,
                                             Ybuf, stats + 4 * 512, 256);
  bn_relu<<<2500, 256, 0, stream>>>(Ybuf, stats + 4 * 512, bf2_g, bf2_b,
                                    out_desc, descb, 256);

  // fc3 two-pass: (1) rowsum of exp(logit-20) with no stores; (2) recompute + store normalized
  fc3_k<false><<<dim3(79, 79), 256, 0, stream>>>(descb, wT, fc3_b, rowsum, nullptr);
  fc3_k<true><<<dim3(79, 79), 256, 0, stream>>>(descb, wT, fc3_b, rowsum, out_lsm);
}

// Round 5
// 1015.694 us; speedup vs baseline: 1.1383x; 1.1383x over previous
//
#include <hip/hip_runtime.h>
#include <hip/hip_bf16.h>

#define NV 10000
#define PADM 10112   // 79*128, fc3 tiling pad

typedef __attribute__((ext_vector_type(8))) short bf16x8;
typedef __attribute__((ext_vector_type(4))) float f32x4;

__device__ __forceinline__ void g2l16(const void* g, void* l) {
  __builtin_amdgcn_global_load_lds((__attribute__((address_space(1))) void*)(void*)g,
                                   (__attribute__((address_space(3))) void*)l, 16, 0, 0);
}

// ---------------- generic fp32 GEMM: Y = [A1|A2] @ B + bias, + column stats ----------------
// grid.x = ceil(M/64), grid.y = N/64, block 256. K1,K2 multiples of 32; N multiple of 64.
__global__ __launch_bounds__(256) void gemm_f32(
    const float* __restrict__ A1, int K1, const float* __restrict__ A2, int K2,
    const float* __restrict__ B, const float* __restrict__ bias,
    float* __restrict__ Y, float* __restrict__ stats, int N)
{
  __shared__ float As[64][36];   // stride 36: 16B-aligned rows, 2-way-max bank aliasing
  __shared__ float Bs[32][68];
  const int tid = threadIdx.x;
  const int row0 = blockIdx.x * 64;
  const int n0 = blockIdx.y * 64;
  const int tr = tid >> 4, tc = tid & 15;
  const int Ktot = K1 + K2;
  float acc[4][4];
#pragma unroll
  for (int i = 0; i < 4; ++i)
#pragma unroll
    for (int j = 0; j < 4; ++j) acc[i][j] = 0.f;

  for (int k0 = 0; k0 < Ktot; k0 += 32) {
    const float* Ap; int lda, ka;
    if (k0 < K1) { Ap = A1; lda = K1; ka = k0; }
    else         { Ap = A2; lda = K2; ka = k0 - K1; }
    __syncthreads();
    {
      int r = tid >> 3, seg = tid & 7;
#pragma unroll
      for (int h = 0; h < 2; ++h) {
        int rr = r + h * 32;
        int gr = row0 + rr; if (gr > NV - 1) gr = NV - 1;  // clamp; stores guarded
        float4 v = *(const float4*)(Ap + (size_t)gr * lda + ka + seg * 4);
        *(float4*)&As[rr][seg * 4] = v;
      }
      int kr = tid >> 4, cseg = tid & 15;
#pragma unroll
      for (int h = 0; h < 2; ++h) {
        int kk = kr + h * 16;
        float4 v = *(const float4*)(B + (size_t)(k0 + kk) * N + n0 + cseg * 4);
        *(float4*)&Bs[kk][cseg * 4] = v;
      }
    }
    __syncthreads();
#pragma unroll 8
    for (int kk = 0; kk < 32; ++kk) {
      float4 bv = *(const float4*)&Bs[kk][tc * 4];
#pragma unroll
      for (int i = 0; i < 4; ++i) {
        float a = As[tr * 4 + i][kk];
        acc[i][0] = fmaf(a, bv.x, acc[i][0]);
        acc[i][1] = fmaf(a, bv.y, acc[i][1]);
        acc[i][2] = fmaf(a, bv.z, acc[i][2]);
        acc[i][3] = fmaf(a, bv.w, acc[i][3]);
      }
    }
  }
  float bvv[4];
#pragma unroll
  for (int j = 0; j < 4; ++j) bvv[j] = bias[n0 + tc * 4 + j];
  float cs[4] = {0.f, 0.f, 0.f, 0.f}, cq[4] = {0.f, 0.f, 0.f, 0.f};
#pragma unroll
  for (int i = 0; i < 4; ++i) {
    int gr = row0 + tr * 4 + i;
    bool ok = gr < NV;
    float o[4];
#pragma unroll
    for (int j = 0; j < 4; ++j) {
      float v = acc[i][j] + bvv[j];
      o[j] = v;
      if (ok) { cs[j] += v; cq[j] += v * v; }
    }
    if (ok) *(float4*)(Y + (size_t)gr * N + n0 + tc * 4) = make_float4(o[0], o[1], o[2], o[3]);
  }
  // block-level column stat reduction, then one atomic per column
  __syncthreads();
  float* red = &As[0][0];  // reuse: need 2176 <= 2304 floats
#pragma unroll
  for (int j = 0; j < 4; ++j) {
    red[tr * 68 + tc * 4 + j] = cs[j];
    red[1088 + tr * 68 + tc * 4 + j] = cq[j];
  }
  __syncthreads();
  if (tid < 64) {
    float s = 0.f, q = 0.f;
#pragma unroll
    for (int t = 0; t < 16; ++t) { s += red[t * 68 + tid]; q += red[1088 + t * 68 + tid]; }
    atomicAdd(&stats[n0 + tid], s);
    atomicAdd(&stats[256 + n0 + tid], q);
  }
}

// ---------------- BN(training stats) + ReLU; optional bf16 secondary output ----------------
__global__ __launch_bounds__(256) void bn_relu(
    const float* __restrict__ Y, const float* __restrict__ stats,
    const float* __restrict__ g, const float* __restrict__ bt,
    float* __restrict__ out, unsigned short* __restrict__ outb, int C)
{
  int gid = blockIdx.x * 256 + threadIdx.x;
  int total = NV * (C >> 2);
  if (gid >= total) return;
  int c = (gid * 4) % C;
  float4 y = *(const float4*)(Y + (size_t)gid * 4);
  float vy[4] = {y.x, y.y, y.z, y.w};
  float o[4];
#pragma unroll
  for (int j = 0; j < 4; ++j) {
    int cc = c + j;
    float mean = stats[cc] * 1e-4f;
    float var  = stats[256 + cc] * 1e-4f - mean * mean;
    float sc = rsqrtf(var + 1e-3f) * g[cc];
    float sh = bt[cc] - mean * sc;
    o[j] = fmaxf(0.f, fmaf(vy[j], sc, sh));
  }
  *(float4*)(out + (size_t)gid * 4) = make_float4(o[0], o[1], o[2], o[3]);
  if (outb != nullptr) {
    unsigned short u[4];
#pragma unroll
    for (int j = 0; j < 4; ++j) {
      __hip_bfloat16 h = __float2bfloat16(o[j]);
      u[j] = *(unsigned short*)&h;
    }
    *(ushort2*)(outb + (size_t)gid * 4)     = make_ushort2(u[0], u[1]);
    *(ushort2*)(outb + (size_t)gid * 4 + 2) = make_ushort2(u[2], u[3]);
  }
}

// ---------------- split-K [64,10000]@[10000,64] -> atomic accumulate into outm[4096] ----------------
__global__ __launch_bounds__(256) void dx_atomic(
    const float* __restrict__ Dm, const float* __restrict__ X, float* __restrict__ outm)
{
  __shared__ float Ds[64][40];
  __shared__ float Xs[40][64];
  const int tid = threadIdx.x;
  const int k0 = blockIdx.x * 40;
  const float* xp = X + (size_t)k0 * 64;
  for (int i = tid; i < 2560; i += 256) ((float*)Xs)[i] = xp[i];
  {
    int r = tid >> 2, qq = tid & 3;
#pragma unroll
    for (int m = 0; m < 10; ++m) Ds[r][qq + 4 * m] = Dm[(size_t)r * NV + k0 + qq + 4 * m];
  }
  __syncthreads();
  const int j = tid & 63, ig = tid >> 6;
  float acc[16];
#pragma unroll
  for (int ii = 0; ii < 16; ++ii) acc[ii] = 0.f;
  for (int k = 0; k < 40; ++k) {
    float xv = Xs[k][j];
#pragma unroll
    for (int ii = 0; ii < 16; ++ii) acc[ii] = fmaf(Ds[ig * 16 + ii][k], xv, acc[ii]);
  }
  float* op = outm + (size_t)ig * 1024 + j;
#pragma unroll
  for (int ii = 0; ii < 16; ++ii) atomicAdd(&op[ii * 64], acc[ii]);
}

// ---------------- layer-independent A_k chain: A_{k+1} = 2E(a_k I + DV A_k) - A_{k-1} ----------------
__global__ __launch_bounds__(256) void chainA(
    const float* __restrict__ DVm, const float* __restrict__ eigs, float* __restrict__ Acat)
{
  __shared__ float DVL[64][68];
  __shared__ float AL[3][64][68];
  __shared__ float ev[64];
  const int tid = threadIdx.x;
  for (int i = tid; i < 4096; i += 256) DVL[i >> 6][i & 63] = DVm[i];
  if (tid < 64) ev[tid] = eigs[tid];
  __syncthreads();
  for (int i = tid; i < 4096; i += 256) {
    int r = i >> 6, c = i & 63;
    AL[0][r][c] = 0.f;
    float v = (r == c) ? ev[r] : 0.f;   // A_1 = diag(eigs)
    AL[1][r][c] = v;
    Acat[i] = v;
  }
  __syncthreads();
  const int tr = tid >> 4, tc = tid & 15;
  float aK[4]; aK[0] = 0.f; aK[1] = -1.f; aK[2] = 0.f; aK[3] = 1.f;  // a_1..a_4
  for (int k = 1; k <= 4; ++k) {
    int cur = k % 3, prv = (k - 1) % 3, nxt = (k + 1) % 3;
    float g4[4][4];
#pragma unroll
    for (int ii = 0; ii < 4; ++ii)
#pragma unroll
      for (int jj = 0; jj < 4; ++jj) g4[ii][jj] = 0.f;
    for (int p = 0; p < 64; ++p) {
      float4 av = *(const float4*)&AL[cur][p][tc * 4];
#pragma unroll
      for (int ii = 0; ii < 4; ++ii) {
        float dv = DVL[tr * 4 + ii][p];
        g4[ii][0] = fmaf(dv, av.x, g4[ii][0]);
        g4[ii][1] = fmaf(dv, av.y, g4[ii][1]);
        g4[ii][2] = fmaf(dv, av.z, g4[ii][2]);
        g4[ii][3] = fmaf(dv, av.w, g4[ii][3]);
      }
    }
    float ak = aK[k - 1];
#pragma unroll
    for (int ii = 0; ii < 4; ++ii) {
      int i = tr * 4 + ii;
#pragma unroll
      for (int jj = 0; jj < 4; ++jj) {
        int j = tc * 4 + jj;
        float gg = g4[ii][jj] + ((i == j) ? ak : 0.f);
        float v = 2.f * ev[i] * gg - AL[prv][i][j];
        AL[nxt][i][j] = v;
        Acat[(size_t)k * 4096 + i * 64 + j] = v;
      }
    }
    __syncthreads();
  }
}

// ---------------- per-layer: M_k = A_k @ S0 -> Mcat[64][320] ----------------
__global__ __launch_bounds__(256) void mcat_k(
    const float* __restrict__ Acat, const float* __restrict__ S0, float* __restrict__ Mcat)
{
  __shared__ float AL[64][68];
  __shared__ float SL[64][68];
  const int kb = blockIdx.x;  // 0..4
  const int tid = threadIdx.x;
  for (int i = tid; i < 4096; i += 256) {
    AL[i >> 6][i & 63] = Acat[(size_t)kb * 4096 + i];
    SL[i >> 6][i & 63] = S0[i];
  }
  __syncthreads();
  const int tr = tid >> 4, tc = tid & 15;
  float g4[4][4];
#pragma unroll
  for (int ii = 0; ii < 4; ++ii)
#pragma unroll
    for (int jj = 0; jj < 4; ++jj) g4[ii][jj] = 0.f;
  for (int p = 0; p < 64; ++p) {
    float4 sv = *(const float4*)&SL[p][tc * 4];
#pragma unroll
    for (int ii = 0; ii < 4; ++ii) {
      float a = AL[tr * 4 + ii][p];
      g4[ii][0] = fmaf(a, sv.x, g4[ii][0]);
      g4[ii][1] = fmaf(a, sv.y, g4[ii][1]);
      g4[ii][2] = fmaf(a, sv.z, g4[ii][2]);
      g4[ii][3] = fmaf(a, sv.w, g4[ii][3]);
    }
  }
#pragma unroll
  for (int ii = 0; ii < 4; ++ii)
#pragma unroll
    for (int jj = 0; jj < 4; ++jj)
      Mcat[(size_t)(tr * 4 + ii) * 320 + kb * 64 + tc * 4 + jj] = g4[ii][jj];
}

// ---------------- Bc = [Wh ; Mout]: Wh = W0-W2+W4, Mout = Mcat @ W[1:6] ----------------
__global__ __launch_bounds__(256) void bc_k(
    const float* __restrict__ W, const float* __restrict__ Mcat,
    float* __restrict__ Bc, int Cout)
{
  int e = blockIdx.x * 256 + threadIdx.x;   // grid sized to 128*Cout exactly
  int row = e / Cout, j = e - row * Cout;
  if (row < 64) {
    Bc[e] = W[row * Cout + j] - W[128 * Cout + row * Cout + j] + W[256 * Cout + row * Cout + j];
  } else {
    int i = row - 64;
    const float* wc = W + 64 * Cout + j;
    const float* mr = Mcat + (size_t)i * 320;
    float s = 0.f;
#pragma unroll 8
    for (int qq = 0; qq < 320; ++qq) s = fmaf(mr[qq], wc[(size_t)qq * Cout], s);
    Bc[e] = s;
  }
}

// ---------------- fc3_w [256][10000] fp32 -> wT [10112][256] bf16 (zero pad) ----------------
__global__ __launch_bounds__(256) void cast_transpose_w(
    const float* __restrict__ w, unsigned short* __restrict__ wT)
{
  __shared__ float tile[32][33];
  int n0 = blockIdx.x * 32, k0 = blockIdx.y * 32;
  int t = threadIdx.x;
  int rr = t >> 5, cc = t & 31;
#pragma unroll
  for (int p = 0; p < 4; ++p) {
    int k = k0 + rr + p * 8, n = n0 + cc;
    tile[rr + p * 8][cc] = (n < NV) ? w[(size_t)k * NV + n] : 0.f;
  }
  __syncthreads();
#pragma unroll
  for (int p = 0; p < 4; ++p) {
    int n = n0 + rr + p * 8, k = k0 + cc;
    __hip_bfloat16 h = __float2bfloat16(tile[cc][rr + p * 8]);
    wT[(size_t)n * 256 + k] = *(unsigned short*)&h;
  }
}

// ---------------- fc3 GEMM: single-buffer 32KB LDS (4 blocks/CU) + XCD row-band swizzle ----
// 1-D grid 6320: xcd = bid&7 owns row-tiles [xcd*10, xcd*10+10); s=bid>>3 walks
// (col_tile = s/10, row_in_band = s%10). Per-XCD working set: A-band 640KB (L2-resident)
// + one shared B-tile per col step -> staging loads become L2 hits.
// WRITE=false: rowsum[r] += sum_c exp(logit-20), no stores.
// WRITE=true : recompute logits, store normalized log_softmax directly.
// LDS XOR-swizzled (T2): linear g2l16 dest + swizzled GLOBAL source column; read kb ^ ((row&7)<<3).
template<bool WRITE>
__global__ __launch_bounds__(256) void fc3_k(
    const unsigned short* __restrict__ A, const unsigned short* __restrict__ Bt,
    const float* __restrict__ bias, float* __restrict__ rowsum,
    float* __restrict__ out)
{
  __shared__ unsigned short As[128 * 64];
  __shared__ unsigned short Bs[128 * 64];
  const int bid = blockIdx.x;
  const int xcd = bid & 7;
  const int s   = bid >> 3;          // 0..789
  const int col_t = s / 10;          // 0..78
  const int row_t = xcd * 10 + (s - col_t * 10);  // 0..79 (79 = pad band)
  const int row0 = row_t * 128, col0 = col_t * 128;
  if (row0 >= NV) return;            // uniform whole-block exit, before any barrier

  const int tid = threadIdx.x;
  const int wv = tid >> 6, lane = tid & 63;
  const int wr = wv >> 1, wc = wv & 1;
  f32x4 acc[4][4];
#pragma unroll
  for (int i = 0; i < 4; ++i)
#pragma unroll
    for (int j = 0; j < 4; ++j)
#pragma unroll
      for (int e = 0; e < 4; ++e) acc[i][j][e] = 0.f;

  const int rs = wv * 8 + (lane >> 3);                   // 0..31 row-in-group
  const int csg = (lane & 7) * 8;                        // LDS dest col (linear, HW order)
  const int gsg = ((lane & 7) ^ (lane >> 3)) * 8;        // swizzled global source col
  const int swz = (lane & 7) << 3;                       // read-side XOR (row&7)<<3
  const unsigned short* Ag = A  + (size_t)(row0 + rs) * 256 + gsg;
  const unsigned short* Bg = Bt + (size_t)(col0 + rs) * 256 + gsg;
  const int mbase = wr * 64 + (lane & 15);
  const int nbase = wc * 64 + (lane & 15);

  for (int k0 = 0; k0 < 256; k0 += 64) {
    __syncthreads();   // WAR: all waves done reading previous tile
#pragma unroll
    for (int i = 0; i < 4; ++i) {
      g2l16(Ag + (size_t)(i * 32) * 256 + k0, &As[(i * 32 + rs) * 64 + csg]);
      g2l16(Bg + (size_t)(i * 32) * 256 + k0, &Bs[(i * 32 + rs) * 64 + csg]);
    }
    asm volatile("s_waitcnt vmcnt(0)" ::: "memory");
    __syncthreads();   // RAW: tile resident for all waves
    __builtin_amdgcn_s_setprio(1);
#pragma unroll
    for (int kk = 0; kk < 2; ++kk) {
      const int kb = (kk * 32 + (lane >> 4) * 8) ^ swz;
      bf16x8 af[4], bf[4];
#pragma unroll
      for (int mi = 0; mi < 4; ++mi) af[mi] = *(const bf16x8*)&As[(mbase + mi * 16) * 64 + kb];
#pragma unroll
      for (int ni = 0; ni < 4; ++ni) bf[ni] = *(const bf16x8*)&Bs[(nbase + ni * 16) * 64 + kb];
#pragma unroll
      for (int mi = 0; mi < 4; ++mi)
#pragma unroll
        for (int ni = 0; ni < 4; ++ni)
          acc[mi][ni] = __builtin_amdgcn_mfma_f32_16x16x32_bf16(af[mi], bf[ni], acc[mi][ni], 0, 0, 0);
    }
    __builtin_amdgcn_s_setprio(0);
  }
  const int q = lane >> 4, cl = lane & 15;
#pragma unroll
  for (int mi = 0; mi < 4; ++mi) {
#pragma unroll
    for (int r = 0; r < 4; ++r) {
      int grow = row0 + wr * 64 + mi * 16 + q * 4 + r;
      if (WRITE) {
        if (grow < NV) {
          float l = 20.f + __logf(rowsum[grow]);
#pragma unroll
          for (int ni = 0; ni < 4; ++ni) {
            int gcol = col0 + wc * 64 + ni * 16 + cl;
            if (gcol < NV)
              out[(size_t)grow * NV + gcol] = acc[mi][ni][r] + bias[gcol] - l;
          }
        }
      } else {
        float ps = 0.f;
        if (grow < NV) {
#pragma unroll
          for (int ni = 0; ni < 4; ++ni) {
            int gcol = col0 + wc * 64 + ni * 16 + cl;
            if (gcol < NV) ps += __expf(acc[mi][ni][r] + bias[gcol] - 20.f);
          }
        }
#pragma unroll
        for (int sh = 1; sh < 16; sh <<= 1) ps += __shfl_xor(ps, sh, 64);
        if (cl == 0 && grow < NV) atomicAdd(&rowsum[grow], ps);
      }
    }
  }
}

extern "C" void kernel_launch(void* const* d_in, const int* in_sizes, int n_in,
                              void* d_out, int out_size, void* d_ws, size_t ws_size,
                              hipStream_t stream)
{
  const float* x     = (const float*)d_in[0];
  const float* V     = (const float*)d_in[1];
  const float* D     = (const float*)d_in[2];
  const float* eigs  = (const float*)d_in[3];
  const float* fc1_w = (const float*)d_in[4];
  const float* fc1_b = (const float*)d_in[5];
  const float* bf1_g = (const float*)d_in[6];
  const float* bf1_b = (const float*)d_in[7];
  const float* W1    = (const float*)d_in[8];
  const float* cb1   = (const float*)d_in[9];
  const float* b1_g  = (const float*)d_in[10];
  const float* b1_b  = (const float*)d_in[11];
  const float* W2    = (const float*)d_in[12];
  const float* cb2   = (const float*)d_in[13];
  const float* b2_g  = (const float*)d_in[14];
  const float* b2_b  = (const float*)d_in[15];
  const float* W3    = (const float*)d_in[16];
  const float* cb3   = (const float*)d_in[17];
  const float* b3_g  = (const float*)d_in[18];
  const float* b3_b  = (const float*)d_in[19];
  const float* fc2_w = (const float*)d_in[20];
  const float* fc2_b = (const float*)d_in[21];
  const float* bf2_g = (const float*)d_in[22];
  const float* bf2_b = (const float*)d_in[23];
  const float* fc3_w = (const float*)d_in[24];
  const float* fc3_b = (const float*)d_in[25];
  (void)in_sizes; (void)n_in; (void)out_size;

  float* ws = (float*)d_ws;
  float* rowsum = ws;                 // [10000]          (zeroed)
  float* stats  = ws + 10000;         // [5][512]         (zeroed)
  float* DVm    = ws + 12560;         // [4096]           (zeroed, atomic acc)
  float* S0a    = ws + 16656;         // [4096]           (zeroed, atomic acc)
  float* S0b    = ws + 20752;         // [4096]           (zeroed, atomic acc)
  float* S0c    = ws + 24848;         // [4096]           (zeroed, atomic acc)
  float* Acat   = ws + 28944;         // [5*4096]
  float* Mcat   = ws + 49424;         // [64*320]
  float* Bc     = ws + 69904;         // [128*128]
  float* Ybuf   = ws + 86288;         // [10000*256]
  float* actA   = ws + 2646288;       // [10000*64]
  float* actB   = ws + 3286288;       // [10000*64]
  float* h3     = ws + 3926288;       // [10000*128]
  unsigned short* descb = (unsigned short*)(ws + 5206288);  // [10112*256] bf16
  unsigned short* wT    = (unsigned short*)(ws + 6500624);  // [10112*256] bf16
  if (ws_size < (size_t)7794960 * 4) return;  // need ~31.2 MB

  float* out_lsm  = (float*)d_out;
  float* out_desc = out_lsm + (size_t)100000000;

  // zero accumulators (rowsum, stats, DVm, S0a/b/c) + bf16 pad rows of desc
  hipMemsetAsync(ws, 0, 28944 * sizeof(float), stream);
  hipMemsetAsync(descb + (size_t)NV * 256, 0, (size_t)(PADM - NV) * 256 * 2, stream);

  cast_transpose_w<<<dim3(316, 8), 256, 0, stream>>>(fc3_w, wT);

  // DV = D @ V, then the layer-independent A_k chain
  dx_atomic<<<250, 256, 0, stream>>>(D, V, DVm);
  chainA<<<1, 256, 0, stream>>>(DVm, eigs, Acat);

  // fc1 + BN + relu
  gemm_f32<<<dim3(157, 1), 256, 0, stream>>>(x, 352, nullptr, 0, fc1_w, fc1_b,
                                             Ybuf, stats + 0 * 512, 64);
  bn_relu<<<625, 256, 0, stream>>>(Ybuf, stats + 0 * 512, bf1_g, bf1_b, actA, nullptr, 64);

  // cheb layer 1 (in actA -> out actB)
  dx_atomic<<<250, 256, 0, stream>>>(D, actA, S0a);
  mcat_k<<<5, 256, 0, stream>>>(Acat, S0a, Mcat);
  bc_k<<<32, 256, 0, stream>>>(W1, Mcat, Bc, 64);
  gemm_f32<<<dim3(157, 1), 256, 0, stream>>>(actA, 64, V, 64, Bc, cb1,
                                             Ybuf, stats + 1 * 512, 64);
  bn_relu<<<625, 256, 0, stream>>>(Ybuf, stats + 1 * 512, b1_g, b1_b, actB, nullptr, 64);

  // cheb layer 2 (actB -> actA)
  dx_atomic<<<250, 256, 0, stream>>>(D, actB, S0b);
  mcat_k<<<5, 256, 0, stream>>>(Acat, S0b, Mcat);
  bc_k<<<32, 256, 0, stream>>>(W2, Mcat, Bc, 64);
  gemm_f32<<<dim3(157, 1), 256, 0, stream>>>(actB, 64, V, 64, Bc, cb2,
                                             Ybuf, stats + 2 * 512, 64);
  bn_relu<<<625, 256, 0, stream>>>(Ybuf, stats + 2 * 512, b2_g, b2_b, actA, nullptr, 64);

  // cheb layer 3 (actA -> h3, Cout=128)
  dx_atomic<<<250, 256, 0, stream>>>(D, actA, S0c);
  mcat_k<<<5, 256, 0, stream>>>(Acat, S0c, Mcat);
  bc_k<<<64, 256, 0, stream>>>(W3, Mcat, Bc, 128);
  gemm_f32<<<dim3(157, 2), 256, 0, stream>>>(actA, 64, V, 64, Bc, cb3,
                                             Ybuf, stats + 3 * 512, 128);
  bn_relu<<<1250, 256, 0, stream>>>(Ybuf, stats + 3 * 512, b3_g, b3_b, h3, nullptr, 128);

  // fc2 + BN + relu -> desc (fp32 to d_out, bf16 to ws)
  gemm_f32<<<dim3(157, 4), 256, 0, stream>>>(h3, 128, nullptr, 0, fc2_w, fc2_b,
                                             Ybuf, stats + 4 * 512, 256);
  bn_relu<<<2500, 256, 0, stream>>>(Ybuf, stats + 4 * 512, bf2_g, bf2_b,
                                    out_desc, descb, 256);

  // fc3 two-pass: (1) rowsum of exp(logit-20) with no stores; (2) recompute + store normalized
  // 6320 = 8 XCD bands x 10 row-tiles x 79 col-tiles (80th row-tile band exits early)
  fc3_k<false><<<6320, 256, 0, stream>>>(descb, wT, fc3_b, rowsum, nullptr);
  fc3_k<true><<<6320, 256, 0, stream>>>(descb, wT, fc3_b, rowsum, out_lsm);
}